// Round 1
// baseline (4001.263 us; speedup 1.0000x reference)
//
#include <hip/hip_runtime.h>

#define N_NODES 50000
#define N_EDGES 800000
#define FEAT 64
#define HID 128
#define N_TYPES 4
#define N_REL 3
#define N_LAYERS 2
#define LN_EPS 1e-5f

// ---------------------------------------------------------------------------
// deg[dst] += 1 over all edges
__global__ void deg_kernel(const int* __restrict__ dst, float* __restrict__ deg) {
    int e = blockIdx.x * blockDim.x + threadIdx.x;
    if (e < N_EDGES) atomicAdd(&deg[dst[e]], 1.0f);
}

// ---------------------------------------------------------------------------
// Encoder pass 1: h[n][j] = relu(b1[t][j] + sum_k z_embed[z[n]][k] * w1[t][k][j])
__global__ void enc1_kernel(const int* __restrict__ z, const int* __restrict__ nt,
                            const float* __restrict__ z_embed,
                            const float* __restrict__ w1, const float* __restrict__ b1,
                            float* __restrict__ h) {
    int idx = blockIdx.x * blockDim.x + threadIdx.x;
    int n = idx >> 7;
    int j = idx & 127;
    if (n >= N_NODES) return;
    int t = nt[n];
    const float* raw = z_embed + (size_t)z[n] * FEAT;
    const float* W = w1 + (size_t)t * FEAT * HID;
    float acc = b1[t * HID + j];
#pragma unroll 8
    for (int k = 0; k < FEAT; ++k) acc += raw[k] * W[k * HID + j];
    h[(size_t)n * HID + j] = fmaxf(acc, 0.0f);
}

// Encoder pass 2: x[n][j] = b2[t][j] + sum_k h[n][k] * w2[t][k][j]
__global__ void enc2_kernel(const int* __restrict__ nt, const float* __restrict__ h,
                            const float* __restrict__ w2, const float* __restrict__ b2,
                            float* __restrict__ x) {
    int idx = blockIdx.x * blockDim.x + threadIdx.x;
    int n = idx >> 7;
    int j = idx & 127;
    if (n >= N_NODES) return;
    int t = nt[n];
    const float* hr = h + (size_t)n * HID;
    const float* W = w2 + (size_t)t * HID * HID;
    float acc = b2[t * HID + j];
#pragma unroll 8
    for (int k = 0; k < HID; ++k) acc += hr[k] * W[k * HID + j];
    x[(size_t)n * HID + j] = acc;
}

// ---------------------------------------------------------------------------
// Y[n][h] = (bias ? bias[h] : 0) + sum_k X[n][k] * W[k][h]   for 128x128 W.
// W staged in LDS (64KB). 8 nodes per tile; each thread: 4 rows x 1 col.
__global__ __launch_bounds__(256) void gemm128_kernel(const float* __restrict__ X,
                                                      const float* __restrict__ W,
                                                      const float* __restrict__ bias,
                                                      float* __restrict__ Y, int nrows) {
    __shared__ float Ws[HID * HID];  // 65536 bytes
    for (int i = threadIdx.x; i < HID * HID; i += 256) Ws[i] = W[i];
    __syncthreads();

    int h = threadIdx.x & 127;
    int half = threadIdx.x >> 7;
    float bv = bias ? bias[h] : 0.0f;
    int ntiles = nrows >> 3;  // nrows = 50000 divisible by 8

    for (int tile = blockIdx.x; tile < ntiles; tile += gridDim.x) {
        int n0 = tile * 8 + half * 4;
        const float4* x0 = (const float4*)(X + (size_t)(n0 + 0) * HID);
        const float4* x1 = (const float4*)(X + (size_t)(n0 + 1) * HID);
        const float4* x2 = (const float4*)(X + (size_t)(n0 + 2) * HID);
        const float4* x3 = (const float4*)(X + (size_t)(n0 + 3) * HID);
        float acc0 = bv, acc1 = bv, acc2 = bv, acc3 = bv;
#pragma unroll
        for (int k = 0; k < HID; k += 4) {
            float4 a0 = x0[k >> 2];
            float4 a1 = x1[k >> 2];
            float4 a2 = x2[k >> 2];
            float4 a3 = x3[k >> 2];
            float w0 = Ws[(k + 0) * HID + h];
            float w1 = Ws[(k + 1) * HID + h];
            float w2 = Ws[(k + 2) * HID + h];
            float w3 = Ws[(k + 3) * HID + h];
            acc0 += a0.x * w0 + a0.y * w1 + a0.z * w2 + a0.w * w3;
            acc1 += a1.x * w0 + a1.y * w1 + a1.z * w2 + a1.w * w3;
            acc2 += a2.x * w0 + a2.y * w1 + a2.z * w2 + a2.w * w3;
            acc3 += a3.x * w0 + a3.y * w1 + a3.z * w2 + a3.w * w3;
        }
        Y[(size_t)(n0 + 0) * HID + h] = acc0;
        Y[(size_t)(n0 + 1) * HID + h] = acc1;
        Y[(size_t)(n0 + 2) * HID + h] = acc2;
        Y[(size_t)(n0 + 3) * HID + h] = acc3;
    }
}

// ---------------------------------------------------------------------------
// For edges with type r: agg[dst[e]][:] += Y[src[e]][:]  (float4 chunks, atomics)
__global__ void scatter_kernel(const int* __restrict__ src, const int* __restrict__ dst,
                               const int* __restrict__ et, const float* __restrict__ Y,
                               float* __restrict__ agg, int r) {
    int idx = blockIdx.x * blockDim.x + threadIdx.x;
    int e = idx >> 5;  // 32 float4 chunks per edge (128 floats)
    if (e >= N_EDGES) return;
    if (et[e] != r) return;
    int c = idx & 31;
    const float4 v = ((const float4*)(Y + (size_t)src[e] * HID))[c];
    float* ap = agg + (size_t)dst[e] * HID + c * 4;
    atomicAdd(ap + 0, v.x);
    atomicAdd(ap + 1, v.y);
    atomicAdd(ap + 2, v.z);
    atomicAdd(ap + 3, v.w);
}

// ---------------------------------------------------------------------------
// LayerNorm: x[n] = LN(Z[n] + agg[n]/max(deg[n],1)) * g + b   (one wave per node)
__global__ __launch_bounds__(256) void ln_kernel(const float* __restrict__ Z,
                                                 const float* __restrict__ agg,
                                                 const float* __restrict__ deg,
                                                 const float* __restrict__ g,
                                                 const float* __restrict__ b,
                                                 float* __restrict__ X) {
    int node = (blockIdx.x * blockDim.x + threadIdx.x) >> 6;
    int lane = threadIdx.x & 63;
    if (node >= N_NODES) return;
    float inv = 1.0f / fmaxf(deg[node], 1.0f);
    size_t base = (size_t)node * HID;
    float v0 = Z[base + lane] + agg[base + lane] * inv;
    float v1 = Z[base + 64 + lane] + agg[base + 64 + lane] * inv;
    float s = v0 + v1;
#pragma unroll
    for (int off = 32; off; off >>= 1) s += __shfl_down(s, off);
    float mu = __shfl(s, 0) * (1.0f / HID);
    float d0 = v0 - mu, d1 = v1 - mu;
    float q = d0 * d0 + d1 * d1;
#pragma unroll
    for (int off = 32; off; off >>= 1) q += __shfl_down(q, off);
    float rstd = rsqrtf(__shfl(q, 0) * (1.0f / HID) + LN_EPS);
    X[base + lane] = d0 * rstd * g[lane] + b[lane];
    X[base + 64 + lane] = d1 * rstd * g[64 + lane] + b[64 + lane];
}

// ---------------------------------------------------------------------------
// pooled[h] += sum over this block's nodes of X[n][h]
__global__ __launch_bounds__(256) void pool_kernel(const float* __restrict__ X,
                                                   float* __restrict__ pooled) {
    int h = threadIdx.x & 127;
    int half = threadIdx.x >> 7;
    float acc = 0.0f;
    for (int n = blockIdx.x * 2 + half; n < N_NODES; n += gridDim.x * 2)
        acc += X[(size_t)n * HID + h];
    __shared__ float tmp[256];
    tmp[threadIdx.x] = acc;
    __syncthreads();
    if (half == 0) atomicAdd(&pooled[h], tmp[h] + tmp[128 + h]);
}

// out[0] = (sum_h pooled[h] * reg_w[h]) / N + reg_b[0]
__global__ void final_kernel(const float* __restrict__ pooled, const float* __restrict__ reg_w,
                             const float* __restrict__ reg_b, float* __restrict__ out) {
    int lane = threadIdx.x;  // 64 threads
    float s = pooled[lane] * reg_w[lane] + pooled[64 + lane] * reg_w[64 + lane];
#pragma unroll
    for (int off = 32; off; off >>= 1) s += __shfl_down(s, off);
    if (lane == 0) out[0] = s * (1.0f / N_NODES) + reg_b[0];
}

// ---------------------------------------------------------------------------
extern "C" void kernel_launch(void* const* d_in, const int* in_sizes, int n_in,
                              void* d_out, int out_size, void* d_ws, size_t ws_size,
                              hipStream_t stream) {
    const int* z = (const int*)d_in[0];
    const int* nt = (const int*)d_in[1];
    const int* ei = (const int*)d_in[2];
    const int* et = (const int*)d_in[3];
    const float* z_embed = (const float*)d_in[4];
    const float* enc_w1 = (const float*)d_in[5];
    const float* enc_b1 = (const float*)d_in[6];
    const float* enc_w2 = (const float*)d_in[7];
    const float* enc_b2 = (const float*)d_in[8];
    const float* lin_w = (const float*)d_in[9];
    const float* lin_b = (const float*)d_in[10];
    const float* rel_w = (const float*)d_in[11];
    const float* ln_g = (const float*)d_in[12];
    const float* ln_b = (const float*)d_in[13];
    const float* reg_w = (const float*)d_in[14];
    const float* reg_b = (const float*)d_in[15];
    float* out = (float*)d_out;

    float* ws = (float*)d_ws;
    const size_t NH = (size_t)N_NODES * HID;
    float* x = ws;             // [N, H]
    float* y = x + NH;         // [N, H] (also reused as Z for lin output)
    float* agg = y + NH;       // [N, H] (also reused as h-buffer for encoder)
    float* deg = agg + NH;     // [N]
    float* pooled = deg + N_NODES;  // [H]

    const int* src = ei;
    const int* dst = ei + N_EDGES;

    // zero deg + pooled (contiguous)
    hipMemsetAsync(deg, 0, (N_NODES + HID) * sizeof(float), stream);
    deg_kernel<<<(N_EDGES + 255) / 256, 256, 0, stream>>>(dst, deg);

    // encoder (h staged in agg buffer)
    enc1_kernel<<<(N_NODES * HID + 255) / 256, 256, 0, stream>>>(z, nt, z_embed, enc_w1,
                                                                 enc_b1, agg);
    enc2_kernel<<<(N_NODES * HID + 255) / 256, 256, 0, stream>>>(nt, agg, enc_w2, enc_b2, x);

    for (int l = 0; l < N_LAYERS; ++l) {
        hipMemsetAsync(agg, 0, NH * sizeof(float), stream);
        for (int r = 0; r < N_REL; ++r) {
            const float* Wr = rel_w + ((size_t)l * N_REL + r) * HID * HID;
            gemm128_kernel<<<512, 256, 0, stream>>>(x, Wr, nullptr, y, N_NODES);
            scatter_kernel<<<(N_EDGES * 32 + 255) / 256, 256, 0, stream>>>(src, dst, et, y,
                                                                           agg, r);
        }
        gemm128_kernel<<<512, 256, 0, stream>>>(x, lin_w + (size_t)l * HID * HID,
                                                lin_b + l * HID, y, N_NODES);
        ln_kernel<<<(N_NODES + 3) / 4, 256, 0, stream>>>(y, agg, deg, ln_g + l * HID,
                                                         ln_b + l * HID, x);
    }

    pool_kernel<<<256, 256, 0, stream>>>(x, pooled);
    final_kernel<<<1, 64, 0, stream>>>(pooled, reg_w, reg_b, out);
}

// Round 2
// 1731.970 us; speedup vs baseline: 2.3102x; 2.3102x over previous
//
#include <hip/hip_runtime.h>

#define N_NODES 50000
#define N_EDGES 800000
#define FEAT 64
#define HID 128
#define N_TYPES 4
#define N_REL 3
#define N_LAYERS 2
#define LN_EPS 1e-5f

// ---------------------------------------------------------------------------
// cnt[dst] += 1 over all edges (int)
__global__ void count_kernel(const int* __restrict__ dst, int* __restrict__ cnt) {
    int e = blockIdx.x * blockDim.x + threadIdx.x;
    if (e < N_EDGES) atomicAdd(&cnt[dst[e]], 1);
}

// Exclusive scan of cnt[N_NODES] -> off[N_NODES+1], also copy to cursor.
// Single block, 1024 threads, chunked + Hillis-Steele over partials.
__global__ __launch_bounds__(1024) void scan_kernel(const int* __restrict__ cnt,
                                                    int* __restrict__ off,
                                                    int* __restrict__ cursor) {
    __shared__ int partial[1024];
    const int CH = (N_NODES + 1023) / 1024;  // 49
    int t = threadIdx.x;
    int base = t * CH;
    int s = 0;
    for (int i = 0; i < CH; ++i) {
        int idx = base + i;
        if (idx < N_NODES) s += cnt[idx];
    }
    partial[t] = s;
    __syncthreads();
    for (int d = 1; d < 1024; d <<= 1) {
        int v = (t >= d) ? partial[t - d] : 0;
        __syncthreads();
        partial[t] += v;
        __syncthreads();
    }
    int run = (t == 0) ? 0 : partial[t - 1];
    for (int i = 0; i < CH; ++i) {
        int idx = base + i;
        if (idx < N_NODES) {
            off[idx] = run;
            cursor[idx] = run;
            run += cnt[idx];
        }
    }
    if (t == 1023) off[N_NODES] = partial[1023];
}

// payload[pos] = src | (et << 16), grouped by dst via cursor
__global__ void fill_kernel(const int* __restrict__ src, const int* __restrict__ dst,
                            const int* __restrict__ et, int* __restrict__ cursor,
                            int* __restrict__ payload) {
    int e = blockIdx.x * blockDim.x + threadIdx.x;
    if (e < N_EDGES) {
        int pos = atomicAdd(&cursor[dst[e]], 1);
        payload[pos] = src[e] | (et[e] << 16);
    }
}

// ---------------------------------------------------------------------------
// Encoder pass 1: h[n][j] = relu(b1[t][j] + sum_k z_embed[z[n]][k] * w1[t][k][j])
__global__ void enc1_kernel(const int* __restrict__ z, const int* __restrict__ nt,
                            const float* __restrict__ z_embed,
                            const float* __restrict__ w1, const float* __restrict__ b1,
                            float* __restrict__ h) {
    int idx = blockIdx.x * blockDim.x + threadIdx.x;
    int n = idx >> 7;
    int j = idx & 127;
    if (n >= N_NODES) return;
    int t = nt[n];
    const float* raw = z_embed + (size_t)z[n] * FEAT;
    const float* W = w1 + (size_t)t * FEAT * HID;
    float acc = b1[t * HID + j];
#pragma unroll 8
    for (int k = 0; k < FEAT; ++k) acc += raw[k] * W[k * HID + j];
    h[(size_t)n * HID + j] = fmaxf(acc, 0.0f);
}

// Encoder pass 2: x[n][j] = b2[t][j] + sum_k h[n][k] * w2[t][k][j]
__global__ void enc2_kernel(const int* __restrict__ nt, const float* __restrict__ h,
                            const float* __restrict__ w2, const float* __restrict__ b2,
                            float* __restrict__ x) {
    int idx = blockIdx.x * blockDim.x + threadIdx.x;
    int n = idx >> 7;
    int j = idx & 127;
    if (n >= N_NODES) return;
    int t = nt[n];
    const float* hr = h + (size_t)n * HID;
    const float* W = w2 + (size_t)t * HID * HID;
    float acc = b2[t * HID + j];
#pragma unroll 8
    for (int k = 0; k < HID; ++k) acc += hr[k] * W[k * HID + j];
    x[(size_t)n * HID + j] = acc;
}

// ---------------------------------------------------------------------------
// Y[n][h] = (bias ? bias[h] : 0) + sum_k X[n][k] * W[k][h]   for 128x128 W.
__global__ __launch_bounds__(256) void gemm128_kernel(const float* __restrict__ X,
                                                      const float* __restrict__ W,
                                                      const float* __restrict__ bias,
                                                      float* __restrict__ Y, int nrows) {
    __shared__ float Ws[HID * HID];  // 65536 bytes
    for (int i = threadIdx.x; i < HID * HID; i += 256) Ws[i] = W[i];
    __syncthreads();

    int h = threadIdx.x & 127;
    int half = threadIdx.x >> 7;
    float bv = bias ? bias[h] : 0.0f;
    int ntiles = nrows >> 3;

    for (int tile = blockIdx.x; tile < ntiles; tile += gridDim.x) {
        int n0 = tile * 8 + half * 4;
        const float4* x0 = (const float4*)(X + (size_t)(n0 + 0) * HID);
        const float4* x1 = (const float4*)(X + (size_t)(n0 + 1) * HID);
        const float4* x2 = (const float4*)(X + (size_t)(n0 + 2) * HID);
        const float4* x3 = (const float4*)(X + (size_t)(n0 + 3) * HID);
        float acc0 = bv, acc1 = bv, acc2 = bv, acc3 = bv;
#pragma unroll
        for (int k = 0; k < HID; k += 4) {
            float4 a0 = x0[k >> 2];
            float4 a1 = x1[k >> 2];
            float4 a2 = x2[k >> 2];
            float4 a3 = x3[k >> 2];
            float w0 = Ws[(k + 0) * HID + h];
            float w1 = Ws[(k + 1) * HID + h];
            float w2 = Ws[(k + 2) * HID + h];
            float w3 = Ws[(k + 3) * HID + h];
            acc0 += a0.x * w0 + a0.y * w1 + a0.z * w2 + a0.w * w3;
            acc1 += a1.x * w0 + a1.y * w1 + a1.z * w2 + a1.w * w3;
            acc2 += a2.x * w0 + a2.y * w1 + a2.z * w2 + a2.w * w3;
            acc3 += a3.x * w0 + a3.y * w1 + a3.z * w2 + a3.w * w3;
        }
        Y[(size_t)(n0 + 0) * HID + h] = acc0;
        Y[(size_t)(n0 + 1) * HID + h] = acc1;
        Y[(size_t)(n0 + 2) * HID + h] = acc2;
        Y[(size_t)(n0 + 3) * HID + h] = acc3;
    }
}

// ---------------------------------------------------------------------------
// One wave per dst node: accumulate y[src] rows for edges of type r.
// agg written (init) or accumulated (r>0). No atomics.
__global__ __launch_bounds__(256) void gather_kernel(const int* __restrict__ off,
                                                     const int* __restrict__ payload,
                                                     const float* __restrict__ y,
                                                     float* __restrict__ agg,
                                                     int r, int init) {
    int node = (blockIdx.x * blockDim.x + threadIdx.x) >> 6;
    int lane = threadIdx.x & 63;
    if (node >= N_NODES) return;
    int e0 = off[node], e1 = off[node + 1];
    float a0 = 0.0f, a1 = 0.0f;
    for (int e = e0; e < e1; ++e) {
        int p = payload[e];
        if ((p >> 16) == r) {  // wave-uniform branch
            const float* yr = y + (size_t)(p & 0xffff) * HID;
            a0 += yr[lane];
            a1 += yr[64 + lane];
        }
    }
    size_t base = (size_t)node * HID;
    if (init) {
        agg[base + lane] = a0;
        agg[base + 64 + lane] = a1;
    } else {
        agg[base + lane] += a0;
        agg[base + 64 + lane] += a1;
    }
}

// ---------------------------------------------------------------------------
// LayerNorm: x[n] = LN(Z[n] + agg[n]/max(cnt[n],1)) * g + b   (one wave per node)
__global__ __launch_bounds__(256) void ln_kernel(const float* __restrict__ Z,
                                                 const float* __restrict__ agg,
                                                 const int* __restrict__ cnt,
                                                 const float* __restrict__ g,
                                                 const float* __restrict__ b,
                                                 float* __restrict__ X) {
    int node = (blockIdx.x * blockDim.x + threadIdx.x) >> 6;
    int lane = threadIdx.x & 63;
    if (node >= N_NODES) return;
    float inv = 1.0f / (float)max(cnt[node], 1);
    size_t base = (size_t)node * HID;
    float v0 = Z[base + lane] + agg[base + lane] * inv;
    float v1 = Z[base + 64 + lane] + agg[base + 64 + lane] * inv;
    float s = v0 + v1;
#pragma unroll
    for (int off = 32; off; off >>= 1) s += __shfl_down(s, off);
    float mu = __shfl(s, 0) * (1.0f / HID);
    float d0 = v0 - mu, d1 = v1 - mu;
    float q = d0 * d0 + d1 * d1;
#pragma unroll
    for (int off = 32; off; off >>= 1) q += __shfl_down(q, off);
    float rstd = rsqrtf(__shfl(q, 0) * (1.0f / HID) + LN_EPS);
    X[base + lane] = d0 * rstd * g[lane] + b[lane];
    X[base + 64 + lane] = d1 * rstd * g[64 + lane] + b[64 + lane];
}

// ---------------------------------------------------------------------------
__global__ __launch_bounds__(256) void pool_kernel(const float* __restrict__ X,
                                                   float* __restrict__ pooled) {
    int h = threadIdx.x & 127;
    int half = threadIdx.x >> 7;
    float acc = 0.0f;
    for (int n = blockIdx.x * 2 + half; n < N_NODES; n += gridDim.x * 2)
        acc += X[(size_t)n * HID + h];
    __shared__ float tmp[256];
    tmp[threadIdx.x] = acc;
    __syncthreads();
    if (half == 0) atomicAdd(&pooled[h], tmp[h] + tmp[128 + h]);
}

__global__ void final_kernel(const float* __restrict__ pooled, const float* __restrict__ reg_w,
                             const float* __restrict__ reg_b, float* __restrict__ out) {
    int lane = threadIdx.x;  // 64 threads
    float s = pooled[lane] * reg_w[lane] + pooled[64 + lane] * reg_w[64 + lane];
#pragma unroll
    for (int off = 32; off; off >>= 1) s += __shfl_down(s, off);
    if (lane == 0) out[0] = s * (1.0f / N_NODES) + reg_b[0];
}

// ---------------------------------------------------------------------------
extern "C" void kernel_launch(void* const* d_in, const int* in_sizes, int n_in,
                              void* d_out, int out_size, void* d_ws, size_t ws_size,
                              hipStream_t stream) {
    const int* z = (const int*)d_in[0];
    const int* nt = (const int*)d_in[1];
    const int* ei = (const int*)d_in[2];
    const int* et = (const int*)d_in[3];
    const float* z_embed = (const float*)d_in[4];
    const float* enc_w1 = (const float*)d_in[5];
    const float* enc_b1 = (const float*)d_in[6];
    const float* enc_w2 = (const float*)d_in[7];
    const float* enc_b2 = (const float*)d_in[8];
    const float* lin_w = (const float*)d_in[9];
    const float* lin_b = (const float*)d_in[10];
    const float* rel_w = (const float*)d_in[11];
    const float* ln_g = (const float*)d_in[12];
    const float* ln_b = (const float*)d_in[13];
    const float* reg_w = (const float*)d_in[14];
    const float* reg_b = (const float*)d_in[15];
    float* out = (float*)d_out;

    const size_t NH = (size_t)N_NODES * HID;
    float* x = (float*)d_ws;       // [N, H]
    float* y = x + NH;             // [N, H] (per-relation message buffer; also lin out; also enc h)
    float* agg = y + NH;           // [N, H]
    float* pooled = agg + NH;      // [H]
    int* cnt = (int*)(pooled + HID);   // [N]
    int* off = cnt + N_NODES;          // [N+1]
    int* cursor = off + N_NODES + 1;   // [N]
    int* payload = cursor + N_NODES;   // [E]

    const int* src = ei;
    const int* dst = ei + N_EDGES;

    // ---- CSR build (dst-sorted) ----
    hipMemsetAsync(cnt, 0, N_NODES * sizeof(int), stream);
    hipMemsetAsync(pooled, 0, HID * sizeof(float), stream);
    count_kernel<<<(N_EDGES + 255) / 256, 256, 0, stream>>>(dst, cnt);
    scan_kernel<<<1, 1024, 0, stream>>>(cnt, off, cursor);
    fill_kernel<<<(N_EDGES + 255) / 256, 256, 0, stream>>>(src, dst, et, cursor, payload);

    // ---- encoder (h staged in y buffer) ----
    enc1_kernel<<<(N_NODES * HID + 255) / 256, 256, 0, stream>>>(z, nt, z_embed, enc_w1,
                                                                 enc_b1, y);
    enc2_kernel<<<(N_NODES * HID + 255) / 256, 256, 0, stream>>>(nt, y, enc_w2, enc_b2, x);

    const int gather_blocks = (N_NODES * 64 + 255) / 256;
    for (int l = 0; l < N_LAYERS; ++l) {
        for (int r = 0; r < N_REL; ++r) {
            const float* Wr = rel_w + ((size_t)l * N_REL + r) * HID * HID;
            gemm128_kernel<<<512, 256, 0, stream>>>(x, Wr, nullptr, y, N_NODES);
            gather_kernel<<<gather_blocks, 256, 0, stream>>>(off, payload, y, agg, r,
                                                             r == 0 ? 1 : 0);
        }
        gemm128_kernel<<<512, 256, 0, stream>>>(x, lin_w + (size_t)l * HID * HID,
                                                lin_b + l * HID, y, N_NODES);
        ln_kernel<<<(N_NODES * 64 + 255) / 256, 256, 0, stream>>>(y, agg, cnt, ln_g + l * HID,
                                                                  ln_b + l * HID, x);
    }

    pool_kernel<<<256, 256, 0, stream>>>(x, pooled);
    final_kernel<<<1, 64, 0, stream>>>(pooled, reg_w, reg_b, out);
}

// Round 3
// 705.591 us; speedup vs baseline: 5.6708x; 2.4546x over previous
//
#include <hip/hip_runtime.h>

#define N_NODES 50000
#define N_EDGES 800000
#define FEAT 64
#define HID 128
#define N_TYPES 4
#define N_REL 3
#define N_LAYERS 2
#define LN_EPS 1e-5f
#define NGROUPS 3125  // 50000 / 16, exact
#define WT_STRIDE 136 // 128 + 8: keeps 16B alignment (136*2=272B) and 2-way-free banks

typedef __attribute__((ext_vector_type(8))) short bf16x8;
typedef __attribute__((ext_vector_type(4))) float f32x4;

// float -> bf16 bits, round-to-nearest-even (finite inputs)
static __device__ inline unsigned short f2bf(float f) {
    unsigned int u = __float_as_uint(f);
    return (unsigned short)((u + 0x7fffu + ((u >> 16) & 1u)) >> 16);
}
static __device__ inline unsigned int packbf2(float lo, float hi) {
    return (unsigned int)f2bf(lo) | ((unsigned int)f2bf(hi) << 16);
}

// ---------------------------------------------------------------------------
// CSR build by destination
__global__ void count_kernel(const int* __restrict__ dst, int* __restrict__ cnt) {
    int e = blockIdx.x * blockDim.x + threadIdx.x;
    if (e < N_EDGES) atomicAdd(&cnt[dst[e]], 1);
}

__global__ __launch_bounds__(1024) void scan_kernel(const int* __restrict__ cnt,
                                                    int* __restrict__ off,
                                                    int* __restrict__ cursor) {
    __shared__ int partial[1024];
    const int CH = (N_NODES + 1023) / 1024;
    int t = threadIdx.x;
    int base = t * CH;
    int s = 0;
    for (int i = 0; i < CH; ++i) {
        int idx = base + i;
        if (idx < N_NODES) s += cnt[idx];
    }
    partial[t] = s;
    __syncthreads();
    for (int d = 1; d < 1024; d <<= 1) {
        int v = (t >= d) ? partial[t - d] : 0;
        __syncthreads();
        partial[t] += v;
        __syncthreads();
    }
    int run = (t == 0) ? 0 : partial[t - 1];
    for (int i = 0; i < CH; ++i) {
        int idx = base + i;
        if (idx < N_NODES) {
            off[idx] = run;
            cursor[idx] = run;
            run += cnt[idx];
        }
    }
    if (t == 1023) off[N_NODES] = partial[1023];
}

__global__ void fill_kernel(const int* __restrict__ src, const int* __restrict__ dst,
                            const int* __restrict__ et, int* __restrict__ cursor,
                            int* __restrict__ payload) {
    int e = blockIdx.x * blockDim.x + threadIdx.x;
    if (e < N_EDGES) {
        int pos = atomicAdd(&cursor[dst[e]], 1);
        payload[pos] = src[e] | (et[e] << 16);  // src < 65536, et < 3
    }
}

// ---------------------------------------------------------------------------
// Encoder collapses to a 400-entry table: combo = z*4 + type.
__global__ __launch_bounds__(128) void enc_table_kernel(const float* __restrict__ z_embed,
                                                        const float* __restrict__ w1,
                                                        const float* __restrict__ b1,
                                                        const float* __restrict__ w2,
                                                        const float* __restrict__ b2,
                                                        unsigned short* __restrict__ xt) {
    int zi = blockIdx.x >> 2;
    int t = blockIdx.x & 3;
    int j = threadIdx.x;
    __shared__ float h[HID];
    float acc = b1[t * HID + j];
#pragma unroll 8
    for (int k = 0; k < FEAT; ++k)
        acc = fmaf(z_embed[zi * FEAT + k], w1[((size_t)t * FEAT + k) * HID + j], acc);
    h[j] = fmaxf(acc, 0.0f);
    __syncthreads();
    float acc2 = b2[t * HID + j];
#pragma unroll 8
    for (int k = 0; k < HID; ++k)
        acc2 = fmaf(h[k], w2[(size_t)t * HID * HID + k * HID + j], acc2);
    xt[blockIdx.x * HID + j] = f2bf(acc2);
}

// xb[n][:] = x_table[z[n]*4 + nt[n]][:]   (uint = 2 bf16 per lane)
__global__ __launch_bounds__(256) void node_fill_kernel(const int* __restrict__ z,
                                                        const int* __restrict__ nt,
                                                        const unsigned int* __restrict__ xtu,
                                                        unsigned int* __restrict__ xbu) {
    int idx = blockIdx.x * blockDim.x + threadIdx.x;
    int node = idx >> 6;
    if (node >= N_NODES) return;
    int lane = idx & 63;
    int combo = z[node] * 4 + nt[node];
    xbu[node * 64 + lane] = xtu[combo * 64 + lane];
}

// ---------------------------------------------------------------------------
// One wave per dst node: s_r[n] = sum of xb[src] over incoming edges of type r,
// all 3 relations in one pass. fp32 accumulate, bf16 store.
__global__ __launch_bounds__(256) void gather3_kernel(const int* __restrict__ off,
                                                      const int* __restrict__ payload,
                                                      const unsigned int* __restrict__ xbu,
                                                      unsigned int* __restrict__ s0,
                                                      unsigned int* __restrict__ s1,
                                                      unsigned int* __restrict__ s2) {
    int node = (blockIdx.x * blockDim.x + threadIdx.x) >> 6;
    if (node >= N_NODES) return;
    int lane = threadIdx.x & 63;
    int e0 = off[node], e1 = off[node + 1];
    float a00 = 0.f, a01 = 0.f, a10 = 0.f, a11 = 0.f, a20 = 0.f, a21 = 0.f;
    for (int e = e0; e < e1; ++e) {
        int p = payload[e];  // wave-uniform -> s_load
        unsigned int v = xbu[(p & 0xffff) * 64 + lane];
        float lo = __uint_as_float(v << 16);
        float hi = __uint_as_float(v & 0xffff0000u);
        int r = p >> 16;  // wave-uniform branch
        if (r == 0) { a00 += lo; a01 += hi; }
        else if (r == 1) { a10 += lo; a11 += hi; }
        else { a20 += lo; a21 += hi; }
    }
    int o = node * 64 + lane;
    s0[o] = packbf2(a00, a01);
    s1[o] = packbf2(a10, a11);
    s2[o] = packbf2(a20, a21);
}

// ---------------------------------------------------------------------------
// MFMA GEMM: OUT[n][h] (+)= sum_k X[n][k] * W[k][h] (+ bias[h])
// X: [N][128] bf16; W: [128][128] fp32 (transposed+cast into LDS); OUT fp32.
// Verified layouts (m89/m91/m120): A[m=lane&15][k=quad*8+j], B[n=lane&15][k=quad*8+j],
// C/D: col=lane&15, row=quad*4+reg.
__global__ __launch_bounds__(256) void mfma_gemm(const unsigned short* __restrict__ X,
                                                 const float* __restrict__ W,
                                                 const float* __restrict__ bias,
                                                 float* __restrict__ OUT, int init) {
    __shared__ unsigned short Wt[HID * WT_STRIDE];  // W^T, bf16, 34816 B
    for (int i = threadIdx.x; i < HID * HID; i += 256) {
        int k = i >> 7, h = i & 127;
        Wt[h * WT_STRIDE + k] = f2bf(W[i]);
    }
    __syncthreads();

    int wave = threadIdx.x >> 6;
    int lane = threadIdx.x & 63;
    int m = lane & 15;
    int quad = lane >> 4;
    int nwaves = gridDim.x * 4;

    for (int g = blockIdx.x * 4 + wave; g < NGROUPS; g += nwaves) {
        int node0 = g * 16;
        const unsigned short* xrow = X + (size_t)(node0 + m) * HID + quad * 8;
        bf16x8 a[4];
#pragma unroll
        for (int kc = 0; kc < 4; ++kc) a[kc] = *(const bf16x8*)(xrow + kc * 32);

#pragma unroll
        for (int ht = 0; ht < 8; ++ht) {
            f32x4 acc = {0.f, 0.f, 0.f, 0.f};
            const unsigned short* wrow = Wt + (ht * 16 + m) * WT_STRIDE + quad * 8;
#pragma unroll
            for (int kc = 0; kc < 4; ++kc) {
                bf16x8 b = *(const bf16x8*)(wrow + kc * 32);
                acc = __builtin_amdgcn_mfma_f32_16x16x32_bf16(a[kc], b, acc, 0, 0, 0);
            }
            float bv = bias ? bias[ht * 16 + m] : 0.0f;
#pragma unroll
            for (int r = 0; r < 4; ++r) {
                size_t o = (size_t)(node0 + quad * 4 + r) * HID + ht * 16 + m;
                float v = acc[r] + bv;
                if (init) OUT[o] = v;
                else OUT[o] += v;
            }
        }
    }
}

// ---------------------------------------------------------------------------
// LayerNorm: xb[n] = bf16( LN(y[n] + agg[n]/max(cnt[n],1)) * g + b )
// lane handles cols {2l, 2l+1}
__global__ __launch_bounds__(256) void ln_kernel(const float* __restrict__ y,
                                                 const float* __restrict__ agg,
                                                 const int* __restrict__ cnt,
                                                 const float* __restrict__ g,
                                                 const float* __restrict__ b,
                                                 unsigned int* __restrict__ xbu) {
    int node = (blockIdx.x * blockDim.x + threadIdx.x) >> 6;
    if (node >= N_NODES) return;
    int lane = threadIdx.x & 63;
    float inv = 1.0f / (float)max(cnt[node], 1);
    float2 v = ((const float2*)y)[node * 64 + lane];
    float2 ag = ((const float2*)agg)[node * 64 + lane];
    v.x += ag.x * inv;
    v.y += ag.y * inv;
    float s = v.x + v.y;
#pragma unroll
    for (int o = 32; o; o >>= 1) s += __shfl_down(s, o);
    float mu = __shfl(s, 0) * (1.0f / HID);
    float dx = v.x - mu, dy = v.y - mu;
    float q = dx * dx + dy * dy;
#pragma unroll
    for (int o = 32; o; o >>= 1) q += __shfl_down(q, o);
    float rstd = rsqrtf(__shfl(q, 0) * (1.0f / HID) + LN_EPS);
    float2 gg = ((const float2*)g)[lane];
    float2 bb = ((const float2*)b)[lane];
    xbu[node * 64 + lane] = packbf2(dx * rstd * gg.x + bb.x, dy * rstd * gg.y + bb.y);
}

// ---------------------------------------------------------------------------
__global__ __launch_bounds__(256) void pool_kernel(const unsigned int* __restrict__ xbu,
                                                   float* __restrict__ pooled) {
    int lane = threadIdx.x & 63;
    int part = threadIdx.x >> 6;
    float a0 = 0.f, a1 = 0.f;
    for (int n = blockIdx.x * 4 + part; n < N_NODES; n += gridDim.x * 4) {
        unsigned int v = xbu[n * 64 + lane];
        a0 += __uint_as_float(v << 16);
        a1 += __uint_as_float(v & 0xffff0000u);
    }
    __shared__ float t0[256], t1[256];
    t0[threadIdx.x] = a0;
    t1[threadIdx.x] = a1;
    __syncthreads();
    if (part == 0) {
        a0 = t0[lane] + t0[64 + lane] + t0[128 + lane] + t0[192 + lane];
        a1 = t1[lane] + t1[64 + lane] + t1[128 + lane] + t1[192 + lane];
        atomicAdd(&pooled[2 * lane], a0);
        atomicAdd(&pooled[2 * lane + 1], a1);
    }
}

__global__ void final_kernel(const float* __restrict__ pooled, const float* __restrict__ reg_w,
                             const float* __restrict__ reg_b, float* __restrict__ out) {
    int lane = threadIdx.x;  // 64
    float s = pooled[lane] * reg_w[lane] + pooled[64 + lane] * reg_w[64 + lane];
#pragma unroll
    for (int o = 32; o; o >>= 1) s += __shfl_down(s, o);
    if (lane == 0) out[0] = s * (1.0f / N_NODES) + reg_b[0];
}

// ---------------------------------------------------------------------------
extern "C" void kernel_launch(void* const* d_in, const int* in_sizes, int n_in,
                              void* d_out, int out_size, void* d_ws, size_t ws_size,
                              hipStream_t stream) {
    const int* z = (const int*)d_in[0];
    const int* nt = (const int*)d_in[1];
    const int* ei = (const int*)d_in[2];
    const int* et = (const int*)d_in[3];
    const float* z_embed = (const float*)d_in[4];
    const float* enc_w1 = (const float*)d_in[5];
    const float* enc_b1 = (const float*)d_in[6];
    const float* enc_w2 = (const float*)d_in[7];
    const float* enc_b2 = (const float*)d_in[8];
    const float* lin_w = (const float*)d_in[9];
    const float* lin_b = (const float*)d_in[10];
    const float* rel_w = (const float*)d_in[11];
    const float* ln_g = (const float*)d_in[12];
    const float* ln_b = (const float*)d_in[13];
    const float* reg_w = (const float*)d_in[14];
    const float* reg_b = (const float*)d_in[15];
    float* out = (float*)d_out;

    const size_t NHb = (size_t)N_NODES * HID;  // elements per [N,H] plane
    char* p = (char*)d_ws;
    unsigned short* xb = (unsigned short*)p;           p += NHb * 2;   // 12.8 MB bf16
    unsigned short* s0 = (unsigned short*)p;           p += NHb * 2;   // 12.8 MB
    unsigned short* s1 = (unsigned short*)p;           p += NHb * 2;   // 12.8 MB
    unsigned short* s2 = (unsigned short*)p;           p += NHb * 2;   // 12.8 MB
    float* agg = (float*)p;                            p += NHb * 4;   // 25.6 MB
    unsigned short* xt = (unsigned short*)p;           p += 400 * HID * 2;
    float* pooled = (float*)p;                         p += HID * 4;
    int* cnt = (int*)p;                                p += N_NODES * 4;
    int* off = (int*)p;                                p += (N_NODES + 1) * 4;
    int* cursor = (int*)p;                             p += N_NODES * 4;
    int* payload = (int*)p;                            p += N_EDGES * 4;
    float* y = (float*)s0;  // 25.6 MB alias over s0+s1 (dead when lin GEMM runs)

    const int* src = ei;
    const int* dst = ei + N_EDGES;

    hipMemsetAsync(cnt, 0, N_NODES * sizeof(int), stream);
    hipMemsetAsync(pooled, 0, HID * sizeof(float), stream);
    count_kernel<<<(N_EDGES + 255) / 256, 256, 0, stream>>>(dst, cnt);
    scan_kernel<<<1, 1024, 0, stream>>>(cnt, off, cursor);
    fill_kernel<<<(N_EDGES + 255) / 256, 256, 0, stream>>>(src, dst, et, cursor, payload);

    enc_table_kernel<<<400, 128, 0, stream>>>(z_embed, enc_w1, enc_b1, enc_w2, enc_b2, xt);
    node_fill_kernel<<<(N_NODES * 64 + 255) / 256, 256, 0, stream>>>(
        z, nt, (const unsigned int*)xt, (unsigned int*)xb);

    const int nwb = (N_NODES * 64 + 255) / 256;  // 12500 blocks: one wave per node
    for (int l = 0; l < N_LAYERS; ++l) {
        gather3_kernel<<<nwb, 256, 0, stream>>>(off, payload, (const unsigned int*)xb,
                                                (unsigned int*)s0, (unsigned int*)s1,
                                                (unsigned int*)s2);
        const float* Wl = rel_w + (size_t)l * N_REL * HID * HID;
        mfma_gemm<<<512, 256, 0, stream>>>(s0, Wl, nullptr, agg, 1);
        mfma_gemm<<<512, 256, 0, stream>>>(s1, Wl + HID * HID, nullptr, agg, 0);
        mfma_gemm<<<512, 256, 0, stream>>>(s2, Wl + 2 * HID * HID, nullptr, agg, 0);
        mfma_gemm<<<512, 256, 0, stream>>>(xb, lin_w + (size_t)l * HID * HID,
                                           lin_b + l * HID, y, 1);
        ln_kernel<<<nwb, 256, 0, stream>>>(y, agg, cnt, ln_g + l * HID, ln_b + l * HID,
                                           (unsigned int*)xb);
    }

    pool_kernel<<<256, 256, 0, stream>>>((const unsigned int*)xb, pooled);
    final_kernel<<<1, 64, 0, stream>>>(pooled, reg_w, reg_b, out);
}

// Round 4
// 514.065 us; speedup vs baseline: 7.7836x; 1.3726x over previous
//
#include <hip/hip_runtime.h>

#define N_NODES 50000
#define N_EDGES 800000
#define FEAT 64
#define HID 128
#define N_TYPES 4
#define N_REL 3
#define N_LAYERS 2
#define LN_EPS 1e-5f
#define NGROUPS 3125  // 50000 / 16, exact
#define NB 196        // ceil(50000/256) scan blocks

typedef __attribute__((ext_vector_type(8))) short bf16x8;
typedef __attribute__((ext_vector_type(4))) float f32x4;

// float -> bf16 bits, round-to-nearest-even (finite inputs)
static __device__ inline unsigned short f2bf(float f) {
    unsigned int u = __float_as_uint(f);
    return (unsigned short)((u + 0x7fffu + ((u >> 16) & 1u)) >> 16);
}
static __device__ inline unsigned int packbf2(float lo, float hi) {
    return (unsigned int)f2bf(lo) | ((unsigned int)f2bf(hi) << 16);
}

// ---------------------------------------------------------------------------
// CSR build by destination
__global__ void count_kernel(const int* __restrict__ dst, int* __restrict__ cnt) {
    int e = blockIdx.x * blockDim.x + threadIdx.x;
    if (e < N_EDGES) atomicAdd(&cnt[dst[e]], 1);
}

// per-256-chunk sums
__global__ __launch_bounds__(256) void scan1_kernel(const int* __restrict__ cnt,
                                                    int* __restrict__ bsum) {
    __shared__ int sh[256];
    int i = blockIdx.x * 256 + threadIdx.x;
    sh[threadIdx.x] = (i < N_NODES) ? cnt[i] : 0;
    __syncthreads();
    for (int d = 128; d; d >>= 1) {
        if (threadIdx.x < d) sh[threadIdx.x] += sh[threadIdx.x + d];
        __syncthreads();
    }
    if (threadIdx.x == 0) bsum[blockIdx.x] = sh[0];
}

// exclusive scan of the 196 block sums
__global__ __launch_bounds__(256) void scan2_kernel(const int* __restrict__ bsum,
                                                    int* __restrict__ boff,
                                                    int* __restrict__ off) {
    __shared__ int sh[256];
    int t = threadIdx.x;
    int v = (t < NB) ? bsum[t] : 0;
    sh[t] = v;
    __syncthreads();
    int acc = v;
    for (int d = 1; d < 256; d <<= 1) {
        int u = (t >= d) ? sh[t - d] : 0;
        __syncthreads();
        acc += u;
        sh[t] = acc;
        __syncthreads();
    }
    if (t < NB) boff[t] = acc - v;  // exclusive
    if (t == 0) off[N_NODES] = N_EDGES;
}

// expand: off[i] = boff[block] + exclusive-prefix-within-block
__global__ __launch_bounds__(256) void scan3_kernel(const int* __restrict__ cnt,
                                                    const int* __restrict__ boff,
                                                    int* __restrict__ off,
                                                    int* __restrict__ cursor) {
    __shared__ int sh[256];
    int i = blockIdx.x * 256 + threadIdx.x;
    int v = (i < N_NODES) ? cnt[i] : 0;
    sh[threadIdx.x] = v;
    __syncthreads();
    int acc = v;
    for (int d = 1; d < 256; d <<= 1) {
        int u = (threadIdx.x >= d) ? sh[threadIdx.x - d] : 0;
        __syncthreads();
        acc += u;
        sh[threadIdx.x] = acc;
        __syncthreads();
    }
    if (i < N_NODES) {
        int excl = boff[blockIdx.x] + acc - v;
        off[i] = excl;
        cursor[i] = excl;
    }
}

__global__ void fill_kernel(const int* __restrict__ src, const int* __restrict__ dst,
                            const int* __restrict__ et, int* __restrict__ cursor,
                            int* __restrict__ payload) {
    int e = blockIdx.x * blockDim.x + threadIdx.x;
    if (e < N_EDGES) {
        int pos = atomicAdd(&cursor[dst[e]], 1);
        payload[pos] = src[e] | (et[e] << 16);  // src < 65536, et < 3
    }
}

// ---------------------------------------------------------------------------
// Encoder collapses to a 400-entry table: combo = z*4 + type.
__global__ __launch_bounds__(128) void enc_table_kernel(const float* __restrict__ z_embed,
                                                        const float* __restrict__ w1,
                                                        const float* __restrict__ b1,
                                                        const float* __restrict__ w2,
                                                        const float* __restrict__ b2,
                                                        unsigned short* __restrict__ xt) {
    int zi = blockIdx.x >> 2;
    int t = blockIdx.x & 3;
    int j = threadIdx.x;
    __shared__ float h[HID];
    float acc = b1[t * HID + j];
#pragma unroll 8
    for (int k = 0; k < FEAT; ++k)
        acc = fmaf(z_embed[zi * FEAT + k], w1[((size_t)t * FEAT + k) * HID + j], acc);
    h[j] = fmaxf(acc, 0.0f);
    __syncthreads();
    float acc2 = b2[t * HID + j];
#pragma unroll 8
    for (int k = 0; k < HID; ++k)
        acc2 = fmaf(h[k], w2[(size_t)t * HID * HID + k * HID + j], acc2);
    xt[blockIdx.x * HID + j] = f2bf(acc2);
}

__global__ __launch_bounds__(256) void node_fill_kernel(const int* __restrict__ z,
                                                        const int* __restrict__ nt,
                                                        const unsigned int* __restrict__ xtu,
                                                        unsigned int* __restrict__ xbu) {
    int idx = blockIdx.x * blockDim.x + threadIdx.x;
    int node = idx >> 6;
    if (node >= N_NODES) return;
    int lane = idx & 63;
    int combo = z[node] * 4 + nt[node];
    xbu[node * 64 + lane] = xtu[combo * 64 + lane];
}

// ---------------------------------------------------------------------------
// One wave per dst node: s_r[n] = sum of xb[src] over incoming edges of type r.
__global__ __launch_bounds__(256) void gather3_kernel(const int* __restrict__ off,
                                                      const int* __restrict__ payload,
                                                      const unsigned int* __restrict__ xbu,
                                                      unsigned int* __restrict__ s0,
                                                      unsigned int* __restrict__ s1,
                                                      unsigned int* __restrict__ s2) {
    int node = (blockIdx.x * blockDim.x + threadIdx.x) >> 6;
    if (node >= N_NODES) return;
    int lane = threadIdx.x & 63;
    int e0 = off[node], e1 = off[node + 1];
    float a00 = 0.f, a01 = 0.f, a10 = 0.f, a11 = 0.f, a20 = 0.f, a21 = 0.f;
    int e = e0;
    for (; e + 2 <= e1; e += 2) {
        int pA = payload[e];
        int pB = payload[e + 1];
        unsigned int vA = xbu[(pA & 0xffff) * 64 + lane];
        unsigned int vB = xbu[(pB & 0xffff) * 64 + lane];
        float loA = __uint_as_float(vA << 16), hiA = __uint_as_float(vA & 0xffff0000u);
        float loB = __uint_as_float(vB << 16), hiB = __uint_as_float(vB & 0xffff0000u);
        int rA = pA >> 16, rB = pB >> 16;  // wave-uniform branches
        if (rA == 0) { a00 += loA; a01 += hiA; }
        else if (rA == 1) { a10 += loA; a11 += hiA; }
        else { a20 += loA; a21 += hiA; }
        if (rB == 0) { a00 += loB; a01 += hiB; }
        else if (rB == 1) { a10 += loB; a11 += hiB; }
        else { a20 += loB; a21 += hiB; }
    }
    if (e < e1) {
        int p = payload[e];
        unsigned int v = xbu[(p & 0xffff) * 64 + lane];
        float lo = __uint_as_float(v << 16), hi = __uint_as_float(v & 0xffff0000u);
        int r = p >> 16;
        if (r == 0) { a00 += lo; a01 += hi; }
        else if (r == 1) { a10 += lo; a11 += hi; }
        else { a20 += lo; a21 += hi; }
    }
    int o = node * 64 + lane;
    s0[o] = packbf2(a00, a01);
    s1[o] = packbf2(a10, a11);
    s2[o] = packbf2(a20, a21);
}

// ---------------------------------------------------------------------------
// Fused layer: for each 16-node group,
//   agg = s0@W0 + s1@W1 + s2@W2 ; y = xb@Wl + lin_b ; v = y + agg/deg ; LN(v)
// Wave w owns column tile ht=w (8 waves, 512 threads). B-fragments in VGPRs.
// If do_pool: accumulate LN output into pooled[] instead of writing xb.
// MFMA layouts (verified m89/m91): A[m=lane&15][k=quad*8+j], B[n][k] same,
// C/D col=lane&15, row=quad*4+reg.
__global__ __launch_bounds__(512) void fused_layer_kernel(
    const unsigned short* __restrict__ s0, const unsigned short* __restrict__ s1,
    const unsigned short* __restrict__ s2, unsigned short* __restrict__ xb,
    const float* __restrict__ W0, const float* __restrict__ W1,
    const float* __restrict__ W2, const float* __restrict__ Wl,
    const float* __restrict__ lb, const int* __restrict__ cnt,
    const float* __restrict__ lng, const float* __restrict__ lnb,
    float* __restrict__ pooled, int do_pool) {
    __shared__ float psum[16][8];
    __shared__ float psq[16][8];
    __shared__ float smu[16];
    __shared__ float srstd[16];

    int wave = threadIdx.x >> 6;  // = ht (column tile)
    int lane = threadIdx.x & 63;
    int m = lane & 15;
    int quad = lane >> 4;
    int col = wave * 16 + m;

    // persistent B fragments: element j of frag kc = W[kc*32+quad*8+j][col]
    bf16x8 B0[4], B1[4], B2[4], BL[4];
#pragma unroll
    for (int kc = 0; kc < 4; ++kc) {
        bf16x8 b0, b1, b2, bl;
#pragma unroll
        for (int j = 0; j < 8; ++j) {
            int idx = (kc * 32 + quad * 8 + j) * HID + col;
            b0[j] = (short)f2bf(W0[idx]);
            b1[j] = (short)f2bf(W1[idx]);
            b2[j] = (short)f2bf(W2[idx]);
            bl[j] = (short)f2bf(Wl[idx]);
        }
        B0[kc] = b0; B1[kc] = b1; B2[kc] = b2; BL[kc] = bl;
    }
    float bv = lb[col];
    float gc = lng[col];
    float bc = lnb[col];
    float pool_acc = 0.0f;

    for (int gi = blockIdx.x; gi < NGROUPS; gi += gridDim.x) {
        int node0 = gi * 16;
        size_t roff = (size_t)(node0 + m) * HID + quad * 8;
        f32x4 accA = {0.f, 0.f, 0.f, 0.f};
        f32x4 accY = {0.f, 0.f, 0.f, 0.f};
#pragma unroll
        for (int kc = 0; kc < 4; ++kc) {
            size_t o = roff + kc * 32;
            bf16x8 a0 = *(const bf16x8*)(s0 + o);
            bf16x8 a1 = *(const bf16x8*)(s1 + o);
            bf16x8 a2 = *(const bf16x8*)(s2 + o);
            bf16x8 ax = *(const bf16x8*)(xb + o);
            accA = __builtin_amdgcn_mfma_f32_16x16x32_bf16(a0, B0[kc], accA, 0, 0, 0);
            accA = __builtin_amdgcn_mfma_f32_16x16x32_bf16(a1, B1[kc], accA, 0, 0, 0);
            accA = __builtin_amdgcn_mfma_f32_16x16x32_bf16(a2, B2[kc], accA, 0, 0, 0);
            accY = __builtin_amdgcn_mfma_f32_16x16x32_bf16(ax, BL[kc], accY, 0, 0, 0);
        }
        // v[r] = LN input for row node0+quad*4+r at column col
        float v[4];
#pragma unroll
        for (int r = 0; r < 4; ++r) {
            int row = node0 + quad * 4 + r;
            float inv = 1.0f / (float)max(cnt[row], 1);
            v[r] = accY[r] + bv + accA[r] * inv;
        }
        // row-stats partial over this wave's 16 columns (butterfly within 16-lane group)
#pragma unroll
        for (int r = 0; r < 4; ++r) {
            float s = v[r];
            float q = v[r] * v[r];
#pragma unroll
            for (int o2 = 1; o2 < 16; o2 <<= 1) {
                s += __shfl_xor(s, o2);
                q += __shfl_xor(q, o2);
            }
            if (m == 0) {
                psum[quad * 4 + r][wave] = s;
                psq[quad * 4 + r][wave] = q;
            }
        }
        __syncthreads();  // B1: all reads of xb/LDS for this group done
        if (wave == 0 && lane < 16) {
            float ts = 0.f, tq = 0.f;
#pragma unroll
            for (int w = 0; w < 8; ++w) { ts += psum[lane][w]; tq += psq[lane][w]; }
            float mu = ts * (1.0f / HID);
            float var = tq * (1.0f / HID) - mu * mu;
            smu[lane] = mu;
            srstd[lane] = rsqrtf(var + LN_EPS);
        }
        __syncthreads();  // B2
#pragma unroll
        for (int r = 0; r < 4; ++r) {
            int lrow = quad * 4 + r;
            float outv = (v[r] - smu[lrow]) * srstd[lrow] * gc + bc;
            if (do_pool) {
                pool_acc += outv;
            } else {
                xb[(size_t)(node0 + lrow) * HID + col] = f2bf(outv);
            }
        }
    }

    if (do_pool) {
        // reduce over quads (lanes with same m across the 4 quads)
        pool_acc += __shfl_xor(pool_acc, 16);
        pool_acc += __shfl_xor(pool_acc, 32);
        if (quad == 0) atomicAdd(&pooled[col], pool_acc);
    }
}

// ---------------------------------------------------------------------------
__global__ void final_kernel(const float* __restrict__ pooled, const float* __restrict__ reg_w,
                             const float* __restrict__ reg_b, float* __restrict__ out) {
    int lane = threadIdx.x;  // 64
    float s = pooled[lane] * reg_w[lane] + pooled[64 + lane] * reg_w[64 + lane];
#pragma unroll
    for (int o = 32; o; o >>= 1) s += __shfl_down(s, o);
    if (lane == 0) out[0] = s * (1.0f / N_NODES) + reg_b[0];
}

// ---------------------------------------------------------------------------
extern "C" void kernel_launch(void* const* d_in, const int* in_sizes, int n_in,
                              void* d_out, int out_size, void* d_ws, size_t ws_size,
                              hipStream_t stream) {
    const int* z = (const int*)d_in[0];
    const int* nt = (const int*)d_in[1];
    const int* ei = (const int*)d_in[2];
    const int* et = (const int*)d_in[3];
    const float* z_embed = (const float*)d_in[4];
    const float* enc_w1 = (const float*)d_in[5];
    const float* enc_b1 = (const float*)d_in[6];
    const float* enc_w2 = (const float*)d_in[7];
    const float* enc_b2 = (const float*)d_in[8];
    const float* lin_w = (const float*)d_in[9];
    const float* lin_b = (const float*)d_in[10];
    const float* rel_w = (const float*)d_in[11];
    const float* ln_g = (const float*)d_in[12];
    const float* ln_b = (const float*)d_in[13];
    const float* reg_w = (const float*)d_in[14];
    const float* reg_b = (const float*)d_in[15];
    float* out = (float*)d_out;

    const size_t NHb = (size_t)N_NODES * HID;
    char* p = (char*)d_ws;
    unsigned short* xb = (unsigned short*)p;  p += NHb * 2;
    unsigned short* s0 = (unsigned short*)p;  p += NHb * 2;
    unsigned short* s1 = (unsigned short*)p;  p += NHb * 2;
    unsigned short* s2 = (unsigned short*)p;  p += NHb * 2;
    unsigned short* xt = (unsigned short*)p;  p += 400 * HID * 2;
    float* pooled = (float*)p;                p += HID * 4;
    int* cnt = (int*)p;                       p += N_NODES * 4;
    int* off = (int*)p;                       p += (N_NODES + 1) * 4;
    int* cursor = (int*)p;                    p += N_NODES * 4;
    int* bsum = (int*)p;                      p += NB * 4;
    int* boff = (int*)p;                      p += NB * 4;
    int* payload = (int*)p;                   p += N_EDGES * 4;

    const int* src = ei;
    const int* dst = ei + N_EDGES;

    hipMemsetAsync(cnt, 0, N_NODES * sizeof(int), stream);
    hipMemsetAsync(pooled, 0, HID * sizeof(float), stream);
    count_kernel<<<(N_EDGES + 255) / 256, 256, 0, stream>>>(dst, cnt);
    scan1_kernel<<<NB, 256, 0, stream>>>(cnt, bsum);
    scan2_kernel<<<1, 256, 0, stream>>>(bsum, boff, off);
    scan3_kernel<<<NB, 256, 0, stream>>>(cnt, boff, off, cursor);
    fill_kernel<<<(N_EDGES + 255) / 256, 256, 0, stream>>>(src, dst, et, cursor, payload);

    enc_table_kernel<<<400, 128, 0, stream>>>(z_embed, enc_w1, enc_b1, enc_w2, enc_b2, xt);
    node_fill_kernel<<<(N_NODES * 64 + 255) / 256, 256, 0, stream>>>(
        z, nt, (const unsigned int*)xt, (unsigned int*)xb);

    const int nwb = (N_NODES * 64 + 255) / 256;  // one wave per node
    for (int l = 0; l < N_LAYERS; ++l) {
        gather3_kernel<<<nwb, 256, 0, stream>>>(off, payload, (const unsigned int*)xb,
                                                (unsigned int*)s0, (unsigned int*)s1,
                                                (unsigned int*)s2);
        const float* Wl = rel_w + (size_t)l * N_REL * HID * HID;
        fused_layer_kernel<<<625, 512, 0, stream>>>(
            s0, s1, s2, xb, Wl, Wl + HID * HID, Wl + 2 * HID * HID,
            lin_w + (size_t)l * HID * HID, lin_b + l * HID, cnt,
            ln_g + l * HID, ln_b + l * HID, pooled, l == N_LAYERS - 1 ? 1 : 0);
    }

    final_kernel<<<1, 64, 0, stream>>>(pooled, reg_w, reg_b, out);
}